// Round 17
// baseline (193.462 us; speedup 1.0000x reference)
//
#include <hip/hip_runtime.h>

// KNN argmin over L2, round 17: phaseB chunked register-preload rescore.
// R16 showed phaseB (57us) latency-bound: VGPR=52 -> only ~8 rescore loads
// in flight -> the 64 S_T column loads per candidate block serialize into
// ~16 L2 round-trips. Fix: preload in 4 chunks of 16 float2 (32 VGPRs) with
// an a/b register double-buffer (16 loads back-to-back, one waitcnt per
// chunk, FMAs overlap the next chunk's loads); launch_bounds(256,3).
// Everything else identical to R16 (fp16 single-term filter, certified
// per-query EPS, 128-granular bmin).
//
// Certification: f16 RNE cross error |Δkey| <= 2^-9*1.01*|s||q|;
// EPS_q = 0.005*sqrt(maxS2*|q|^2) + 0.05 >= 2*Δkey_max => rescoring all
// blocks with bmin <= min+EPS_q provably contains the true first argmin.
// Phase B exact fp32 keys, strict-< ascending + lexicographic cross-lane
// => np.argmin first-index semantics.

#define NTOT   16384
#define DIM    64
#define EPS_COEF 0.005f
#define EPS_ABS  0.05f
#define FLT_BIG 3.4e38f

typedef __attribute__((ext_vector_type(8))) short short8;
typedef __attribute__((ext_vector_type(4))) float float4v;

__device__ __forceinline__ ushort f16_bits(float x) {
  union { _Float16 f; ushort u; } c;
  c.f = (_Float16)x;  // v_cvt_f16_f32, RNE
  return c.u;
}

// Opaque def: forbids rematerialization (forces register residency).
__device__ __forceinline__ void pin8(short8& v) {
  asm volatile("" : "+v"(v));
}

// ---------------------------------------------------------------------------
// Fused prep: blocks 0..255 -> S (f16 panels + sqS + S_T + maxS2);
// blocks 256..511 -> Q (f16 panels + sqQ). Panel layout (R8-proven):
//   off(r,k) = (r>>4)*1024 + (k>>5)*512 + (((k&31)>>3)*16 + (r&15))*8 + (k&7)
__global__ __launch_bounds__(256) void k_prep(
    const float* __restrict__ S, const float* __restrict__ Q,
    ushort* __restrict__ Sh, ushort* __restrict__ Qh,
    float* __restrict__ sqS, float* __restrict__ sqQ,
    float* __restrict__ S_T, int* __restrict__ maxS2) {
  __shared__ float tile[64][65];
  const int tid = threadIdx.x;
  const bool isS = blockIdx.x < 256;
  const int rbase = (blockIdx.x & 255) * 64;
  const float* __restrict__ src = isS ? S : Q;
  ushort* __restrict__ dh = isS ? Sh : Qh;

  const int tx = tid & 63;
  const int ty = tid >> 6;
#pragma unroll
  for (int i = 0; i < 16; ++i) {
    const int r = i * 4 + ty;
    tile[r][tx] = src[(size_t)(rbase + r) * DIM + tx];  // coalesced
  }
  __syncthreads();

  if (isS) {  // transposed copy (coalesced, pad-safe)
#pragma unroll
    for (int i = 0; i < 16; ++i) {
      const int d = i * 4 + ty;
      S_T[(size_t)d * NTOT + rbase + tx] = tile[tx][d];
    }
  }

  // Panel-swizzled f16; stores are lane-contiguous 16B.
  const int panel = tid >> 6;           // 0..3
  const int half = (tid >> 5) & 1;      // k-half
  const int slot0 = (tid & 31) * 2;     // slot = q8*16 + m
#pragma unroll
  for (int ss = 0; ss < 2; ++ss) {
    const int s = slot0 + ss;
    const int m = s & 15;
    const int q8 = s >> 4;
    const int row = panel * 16 + m;
    const int kb = half * 32 + q8 * 8;
    short8 hv;
#pragma unroll
    for (int j = 0; j < 8; ++j) hv[j] = (short)f16_bits(tile[row][kb + j]);
    const size_t goff =
        (size_t)((rbase >> 4) + panel) * 1024 + (size_t)half * 512 + (size_t)s * 8;
    *(short8*)&dh[goff] = hv;
  }

  // Row sum of squares (+ S-side global max via atomicMax on int bits).
  if (tid < 64) {
    float acc = 0.0f;
#pragma unroll
    for (int d = 0; d < DIM; ++d) {
      const float v = tile[tid][d];
      acc = fmaf(v, v, acc);
    }
    (isS ? sqS : sqQ)[rbase + tid] = acc;
    if (isS) {
      float mx = acc;
#pragma unroll
      for (int d = 1; d < 64; d <<= 1) mx = fmaxf(mx, __shfl_xor(mx, d, 64));
      if (tid == 0) atomicMax(maxS2, __float_as_int(mx));  // positive floats
    }
  }
}

// ---------------------------------------------------------------------------
// Phase A: block = 4 waves; wave w: 64 queries x 512 supports.
// grid = (8 splits, 256 q-tiles). 16x16x32 f16 MFMA (fragment layout as the
// R4-R16 HW-verified family). C init -0.5*sq hoisted; 2-MFMA chain/tile.

#define MFMA16F(A, B, C) __builtin_amdgcn_mfma_f32_16x16x32_f16(A, B, C, 0, 0, 0)

#define STEP_COMPUTE(H0, H1, SQ)                                           \
  do {                                                                     \
    float4v cinit;                                                         \
    cinit[0] = -0.5f * SQ.x;                                               \
    cinit[1] = -0.5f * SQ.y;                                               \
    cinit[2] = -0.5f * SQ.z;                                               \
    cinit[3] = -0.5f * SQ.w;                                               \
    _Pragma("unroll")                                                      \
    for (int t = 0; t < 4; ++t) {                                          \
      float4v a = MFMA16F(H0, qh[t][0], cinit);                            \
      a = MFMA16F(H1, qh[t][1], a);                                        \
      bmr[t] = fmaxf(bmr[t], fmaxf(fmaxf(a[0], a[1]), fmaxf(a[2], a[3]))); \
    }                                                                      \
  } while (0)

template <int BST>  // steps per bmin block (8 -> 128-support granularity)
__global__ __launch_bounds__(256, 3) void k_phaseA(
    const ushort* __restrict__ Sh, const ushort* __restrict__ Qh,
    const float* __restrict__ sqS, float* __restrict__ bmin) {
  constexpr int NSB = NTOT / (16 * BST);
  const int tid = threadIdx.x;
  const int l = tid & 63;
  const int w = tid >> 6;
  const int lm = l & 15;
  const int lq = l >> 4;
  const int split = blockIdx.x;       // 0..7
  const int qbase = blockIdx.y * 64;
  const int sbase = split * 2048 + w * 512;

  // Query (B) fragments: 4 tiles x 2 k-chunks, pinned (resident).
  short8 qh[4][2];
#pragma unroll
  for (int t = 0; t < 4; ++t) {
    const size_t pb = (size_t)((qbase >> 4) + t) * 1024 + (size_t)l * 8;
    qh[t][0] = *(const short8*)&Qh[pb];
    qh[t][1] = *(const short8*)&Qh[pb + 512];
  }
#pragma unroll
  for (int t = 0; t < 4; ++t) {
    pin8(qh[t][0]);
    pin8(qh[t][1]);
  }

  const ushort* pSh = Sh + (size_t)(sbase >> 4) * 1024 + (size_t)l * 8;
  const float* psq = sqS + sbase + lq * 4;

  // Copy-free double buffer: even steps use (a), odd steps use (b).
  short8 h0a = *(const short8*)(pSh);
  short8 h1a = *(const short8*)(pSh + 512);
  float4 sqa = *(const float4*)(psq);
  short8 h0b = *(const short8*)(pSh + 1024);
  short8 h1b = *(const short8*)(pSh + 1024 + 512);
  float4 sqb = *(const float4*)(psq + 16);

  float bmr[4] = {-FLT_BIG, -FLT_BIG, -FLT_BIG, -FLT_BIG};

  for (int st = 0; st < 32; st += 2) {
    STEP_COMPUTE(h0a, h1a, sqa);
    if (st + 2 < 32) {
      const int off = (st + 2) * 1024;
      h0a = *(const short8*)(pSh + off);
      h1a = *(const short8*)(pSh + off + 512);
      sqa = *(const float4*)(psq + (st + 2) * 16);
    }
    STEP_COMPUTE(h0b, h1b, sqb);
    if (st + 3 < 32) {
      const int off = (st + 3) * 1024;
      h0b = *(const short8*)(pSh + off);
      h1b = *(const short8*)(pSh + off + 512);
      sqb = *(const float4*)(psq + (st + 3) * 16);
    }
    if (((st + 1) & (BST - 1)) == (BST - 1)) {  // finished a bmin block
      const int gb = split * (128 / BST) + w * (32 / BST) + ((st + 1) / BST);
#pragma unroll
      for (int t = 0; t < 4; ++t) {
        float v = bmr[t];
        v = fmaxf(v, __shfl_xor(v, 16, 64));
        v = fmaxf(v, __shfl_xor(v, 32, 64));
        if (lq == 0) bmin[(size_t)(qbase + t * 16 + lm) * NSB + gb] = -2.0f * v;
        bmr[t] = -FLT_BIG;
      }
    }
  }
}

// ---------------------------------------------------------------------------
// Phase B: one wave per query; chunked register-preload rescore from S_T.
// 4 chunks x 16 dims of float2 (32 VGPRs/chunk), a/b double-buffered:
// loads of chunk i+2 issue while chunk i's FMAs run.

#define PB_LOAD(BUF, D0)                                                   \
  do {                                                                     \
    _Pragma("unroll")                                                      \
    for (int j = 0; j < 16; ++j)                                           \
      BUF[j] = *(const float2*)&S_T[(size_t)((D0) + j) * NTOT + s0];       \
  } while (0)

#define PB_FMA(BUF, D0)                                                    \
  do {                                                                     \
    _Pragma("unroll")                                                      \
    for (int j4 = 0; j4 < 4; ++j4) {                                       \
      const float4 qv = *(const float4*)&sQrow[w][(D0) + j4 * 4];          \
      a0 = fmaf(qv.x, BUF[j4 * 4 + 0].x, a0);                              \
      a1 = fmaf(qv.x, BUF[j4 * 4 + 0].y, a1);                              \
      a0 = fmaf(qv.y, BUF[j4 * 4 + 1].x, a0);                              \
      a1 = fmaf(qv.y, BUF[j4 * 4 + 1].y, a1);                              \
      a0 = fmaf(qv.z, BUF[j4 * 4 + 2].x, a0);                              \
      a1 = fmaf(qv.z, BUF[j4 * 4 + 2].y, a1);                              \
      a0 = fmaf(qv.w, BUF[j4 * 4 + 3].x, a0);                              \
      a1 = fmaf(qv.w, BUF[j4 * 4 + 3].y, a1);                              \
    }                                                                      \
  } while (0)

template <int SBLK>
__global__ __launch_bounds__(256, 3) void k_phaseB(
    const float* __restrict__ S_T,   // [64][NTOT]
    const float* __restrict__ Q,     // [NTOT][64]
    const float* __restrict__ sqS, const float* __restrict__ sqQ,
    const int* __restrict__ maxS2, const float* __restrict__ bmin,
    const float* __restrict__ onehot, float* __restrict__ out) {
  constexpr int NSB = NTOT / SBLK;    // 128 or 64
  constexpr int NB64 = NSB / 64;
  constexpr int SPL = SBLK / 64;      // supports per lane: 2 or 4

  __shared__ float sQrow[4][64];
  const int lane = threadIdx.x & 63;
  const int w = threadIdx.x >> 6;
  const int q = blockIdx.x * 4 + w;

  if (lane < 16)
    *(float4*)&sQrow[w][lane * 4] = *(const float4*)&Q[(size_t)q * DIM + lane * 4];
  __syncthreads();

  // Per-query certified filter width.
  const float ms2 = __int_as_float(*maxS2);
  const float eps = EPS_COEF * sqrtf(ms2 * sqQ[q]) + EPS_ABS;

  float bv[NB64];
#pragma unroll
  for (int j = 0; j < NB64; ++j) bv[j] = bmin[(size_t)q * NSB + j * 64 + lane];
  float m = bv[0];
#pragma unroll
  for (int j = 1; j < NB64; ++j) m = fminf(m, bv[j]);
#pragma unroll
  for (int d = 1; d < 64; d <<= 1) m = fminf(m, __shfl_xor(m, d, 64));
  const float thr = m + eps;

  float bk = FLT_BIG;
  int bi = 0;
#pragma unroll
  for (int j = 0; j < NB64; ++j) {
    unsigned long long msk = __ballot(bv[j] <= thr);
    while (msk) {  // ascending block order; wave-uniform control
      const int b = j * 64 + (__ffsll((long long)msk) - 1);
      msk &= msk - 1;
      const int s0 = b * SBLK + lane * SPL;
      if (SPL == 2) {
        float a0 = 0.f, a1 = 0.f;
        float2 va[16], vb[16];
        PB_LOAD(va, 0);            // chunk 0 loads (16 in flight)
        PB_LOAD(vb, 16);           // chunk 1 loads (32 in flight)
        PB_FMA(va, 0);             // compute chunk 0
        PB_LOAD(va, 32);           // prefetch chunk 2
        PB_FMA(vb, 16);            // compute chunk 1
        PB_LOAD(vb, 48);           // prefetch chunk 3
        PB_FMA(va, 32);            // compute chunk 2
        PB_FMA(vb, 48);            // compute chunk 3
        const float2 sq2 = *(const float2*)&sqS[s0];
        const float k0 = fmaf(-2.f, a0, sq2.x);
        const float k1 = fmaf(-2.f, a1, sq2.y);
        bool u;  // ascending index, strict <
        u = k0 < bk; bk = u ? k0 : bk; bi = u ? s0 : bi;
        u = k1 < bk; bk = u ? k1 : bk; bi = u ? (s0 + 1) : bi;
      } else {
        float a0 = 0.f, a1 = 0.f, a2 = 0.f, a3 = 0.f;
#pragma unroll
        for (int c = 0; c < 16; ++c) {
          const float4 qv = *(const float4*)&sQrow[w][c * 4];
          const float4 s0v = *(const float4*)&S_T[(size_t)(c * 4 + 0) * NTOT + s0];
          const float4 s1v = *(const float4*)&S_T[(size_t)(c * 4 + 1) * NTOT + s0];
          const float4 s2v = *(const float4*)&S_T[(size_t)(c * 4 + 2) * NTOT + s0];
          const float4 s3v = *(const float4*)&S_T[(size_t)(c * 4 + 3) * NTOT + s0];
          a0 = fmaf(qv.x, s0v.x, a0); a1 = fmaf(qv.x, s0v.y, a1);
          a2 = fmaf(qv.x, s0v.z, a2); a3 = fmaf(qv.x, s0v.w, a3);
          a0 = fmaf(qv.y, s1v.x, a0); a1 = fmaf(qv.y, s1v.y, a1);
          a2 = fmaf(qv.y, s1v.z, a2); a3 = fmaf(qv.y, s1v.w, a3);
          a0 = fmaf(qv.z, s2v.x, a0); a1 = fmaf(qv.z, s2v.y, a1);
          a2 = fmaf(qv.z, s2v.z, a2); a3 = fmaf(qv.z, s2v.w, a3);
          a0 = fmaf(qv.w, s3v.x, a0); a1 = fmaf(qv.w, s3v.y, a1);
          a2 = fmaf(qv.w, s3v.z, a2); a3 = fmaf(qv.w, s3v.w, a3);
        }
        const float4 sq4 = *(const float4*)&sqS[s0];
        const float k0 = fmaf(-2.f, a0, sq4.x);
        const float k1 = fmaf(-2.f, a1, sq4.y);
        const float k2 = fmaf(-2.f, a2, sq4.z);
        const float k3 = fmaf(-2.f, a3, sq4.w);
        bool u;
        u = k0 < bk; bk = u ? k0 : bk; bi = u ? s0 : bi;
        u = k1 < bk; bk = u ? k1 : bk; bi = u ? (s0 + 1) : bi;
        u = k2 < bk; bk = u ? k2 : bk; bi = u ? (s0 + 2) : bi;
        u = k3 < bk; bk = u ? k3 : bk; bi = u ? (s0 + 3) : bi;
      }
    }
  }
  // Cross-lane lexicographic argmin on exact keys => first-index semantics.
#pragma unroll
  for (int d = 1; d < 64; d <<= 1) {
    const float ok = __shfl_xor(bk, d, 64);
    const int oi = __shfl_xor(bi, d, 64);
    const bool u = (ok < bk) || (ok == bk && oi < bi);
    bk = u ? ok : bk;
    bi = u ? oi : bi;
  }
  // Label: one-hot rows exact {0,1}; first 1 == np.argmax.
  const float ov = onehot[(size_t)bi * 64 + lane];
  const unsigned long long lmask = __ballot(ov > 0.5f);
  const int label = __ffsll((long long)lmask) - 1;
  out[(size_t)q * 64 + lane] = (lane == label) ? 1.0f : 0.0f;
}

// ---------------------------------------------------------------------------
extern "C" void kernel_launch(void* const* d_in, const int* in_sizes, int n_in,
                              void* d_out, int out_size, void* d_ws, size_t ws_size,
                              hipStream_t stream) {
  const float* S = (const float*)d_in[0];   // [16384][64]
  const float* Q = (const float*)d_in[1];   // [16384][64]
  const float* OH = (const float*)d_in[2];  // [16384][64]
  float* out = (float*)d_out;

  char* ws = (char*)d_ws;
  ushort* Sh = (ushort*)ws;                                  // [0, 2MB)
  ushort* Qh = (ushort*)(ws + (2u << 20));                   // [2, 4MB)
  float* S_T = (float*)(ws + (4u << 20));                    // [4, 8MB)
  float* sqS = (float*)(ws + (8u << 20));                    // 64 KB
  float* sqQ = (float*)(ws + (8u << 20) + (64u << 10));      // 64 KB
  int* mS2 = (int*)(ws + (8u << 20) + (128u << 10));         // 64 KB slot
  float* bmin = (float*)(ws + (8u << 20) + (192u << 10));    // up to 8 MB

  hipMemsetAsync(mS2, 0, 4, stream);  // maxS2 accumulator (stream op: ok)
  k_prep<<<dim3(512), 256, 0, stream>>>(S, Q, Sh, Qh, sqS, sqQ, S_T, mS2);

  if (ws_size >= (17u << 20)) {
    k_phaseA<8><<<dim3(8, NTOT / 64), 256, 0, stream>>>(Sh, Qh, sqS, bmin);
    k_phaseB<128><<<dim3(NTOT / 4), 256, 0, stream>>>(S_T, Q, sqS, sqQ, mS2,
                                                      bmin, OH, out);
  } else {
    k_phaseA<16><<<dim3(8, NTOT / 64), 256, 0, stream>>>(Sh, Qh, sqS, bmin);
    k_phaseB<256><<<dim3(NTOT / 4), 256, 0, stream>>>(S_T, Q, sqS, sqQ, mS2,
                                                      bmin, OH, out);
  }
  (void)in_sizes; (void)n_in; (void)out_size; (void)ws_size;
}

// Round 18
// 166.448 us; speedup vs baseline: 1.1623x; 1.1623x over previous
//
#include <hip/hip_runtime.h>

// KNN argmin over L2, round 18: phaseB parallelized across waves (dim-split).
// R17's register-array preload went to scratch (WRITE_SIZE 67MB = spill;
// second instance of the array-in-runtime-loop trap). Fix latency with
// PARALLELISM instead: one block per query; wave w computes partial dots
// over dims [16w,16w+16) (16-load chain vs 64), partials combined via a
// parity-double-buffered LDS array (1 barrier/candidate), wave 0 finishes
// (key, argmin, label, out). All waves read identical bmin -> identical
// ballot masks -> aligned barriers.
// Everything else identical to R16 (best total 161.7us): fp16 single-term
// filter, certified per-query EPS, 128-granular bmin, fused prep.
//
// Certification: f16 RNE cross error |Δkey| <= 2^-9*1.01*|s||q|;
// EPS_q = 0.005*sqrt(maxS2*|q|^2) + 0.05 >= 2*Δkey_max => rescoring all
// blocks with bmin <= min+EPS_q provably contains the true first argmin.
// Phase B exact fp32 keys (deterministic tree-sum), strict-< ascending +
// lexicographic cross-lane => np.argmin first-index semantics.

#define NTOT   16384
#define DIM    64
#define EPS_COEF 0.005f
#define EPS_ABS  0.05f
#define FLT_BIG 3.4e38f

typedef __attribute__((ext_vector_type(8))) short short8;
typedef __attribute__((ext_vector_type(4))) float float4v;

__device__ __forceinline__ ushort f16_bits(float x) {
  union { _Float16 f; ushort u; } c;
  c.f = (_Float16)x;  // v_cvt_f16_f32, RNE
  return c.u;
}

// Opaque def: forbids rematerialization (forces register residency).
__device__ __forceinline__ void pin8(short8& v) {
  asm volatile("" : "+v"(v));
}

// ---------------------------------------------------------------------------
// Fused prep: blocks 0..255 -> S (f16 panels + sqS + S_T + maxS2);
// blocks 256..511 -> Q (f16 panels + sqQ). Panel layout (R8-proven):
//   off(r,k) = (r>>4)*1024 + (k>>5)*512 + (((k&31)>>3)*16 + (r&15))*8 + (k&7)
__global__ __launch_bounds__(256) void k_prep(
    const float* __restrict__ S, const float* __restrict__ Q,
    ushort* __restrict__ Sh, ushort* __restrict__ Qh,
    float* __restrict__ sqS, float* __restrict__ sqQ,
    float* __restrict__ S_T, int* __restrict__ maxS2) {
  __shared__ float tile[64][65];
  const int tid = threadIdx.x;
  const bool isS = blockIdx.x < 256;
  const int rbase = (blockIdx.x & 255) * 64;
  const float* __restrict__ src = isS ? S : Q;
  ushort* __restrict__ dh = isS ? Sh : Qh;

  const int tx = tid & 63;
  const int ty = tid >> 6;
#pragma unroll
  for (int i = 0; i < 16; ++i) {
    const int r = i * 4 + ty;
    tile[r][tx] = src[(size_t)(rbase + r) * DIM + tx];  // coalesced
  }
  __syncthreads();

  if (isS) {  // transposed copy (coalesced, pad-safe)
#pragma unroll
    for (int i = 0; i < 16; ++i) {
      const int d = i * 4 + ty;
      S_T[(size_t)d * NTOT + rbase + tx] = tile[tx][d];
    }
  }

  // Panel-swizzled f16; stores are lane-contiguous 16B.
  const int panel = tid >> 6;           // 0..3
  const int half = (tid >> 5) & 1;      // k-half
  const int slot0 = (tid & 31) * 2;     // slot = q8*16 + m
#pragma unroll
  for (int ss = 0; ss < 2; ++ss) {
    const int s = slot0 + ss;
    const int m = s & 15;
    const int q8 = s >> 4;
    const int row = panel * 16 + m;
    const int kb = half * 32 + q8 * 8;
    short8 hv;
#pragma unroll
    for (int j = 0; j < 8; ++j) hv[j] = (short)f16_bits(tile[row][kb + j]);
    const size_t goff =
        (size_t)((rbase >> 4) + panel) * 1024 + (size_t)half * 512 + (size_t)s * 8;
    *(short8*)&dh[goff] = hv;
  }

  // Row sum of squares (+ S-side global max via atomicMax on int bits).
  if (tid < 64) {
    float acc = 0.0f;
#pragma unroll
    for (int d = 0; d < DIM; ++d) {
      const float v = tile[tid][d];
      acc = fmaf(v, v, acc);
    }
    (isS ? sqS : sqQ)[rbase + tid] = acc;
    if (isS) {
      float mx = acc;
#pragma unroll
      for (int d = 1; d < 64; d <<= 1) mx = fmaxf(mx, __shfl_xor(mx, d, 64));
      if (tid == 0) atomicMax(maxS2, __float_as_int(mx));  // positive floats
    }
  }
}

// ---------------------------------------------------------------------------
// Phase A: block = 4 waves; wave w: 64 queries x 512 supports.
// grid = (8 splits, 256 q-tiles). 16x16x32 f16 MFMA (fragment layout as the
// R4-R17 HW-verified family). C init -0.5*sq hoisted; 2-MFMA chain/tile.
// (Identical to R16 — proven.)

#define MFMA16F(A, B, C) __builtin_amdgcn_mfma_f32_16x16x32_f16(A, B, C, 0, 0, 0)

#define STEP_COMPUTE(H0, H1, SQ)                                           \
  do {                                                                     \
    float4v cinit;                                                         \
    cinit[0] = -0.5f * SQ.x;                                               \
    cinit[1] = -0.5f * SQ.y;                                               \
    cinit[2] = -0.5f * SQ.z;                                               \
    cinit[3] = -0.5f * SQ.w;                                               \
    _Pragma("unroll")                                                      \
    for (int t = 0; t < 4; ++t) {                                          \
      float4v a = MFMA16F(H0, qh[t][0], cinit);                            \
      a = MFMA16F(H1, qh[t][1], a);                                        \
      bmr[t] = fmaxf(bmr[t], fmaxf(fmaxf(a[0], a[1]), fmaxf(a[2], a[3]))); \
    }                                                                      \
  } while (0)

template <int BST>  // steps per bmin block (8 -> 128-support granularity)
__global__ __launch_bounds__(256, 3) void k_phaseA(
    const ushort* __restrict__ Sh, const ushort* __restrict__ Qh,
    const float* __restrict__ sqS, float* __restrict__ bmin) {
  constexpr int NSB = NTOT / (16 * BST);
  const int tid = threadIdx.x;
  const int l = tid & 63;
  const int w = tid >> 6;
  const int lm = l & 15;
  const int lq = l >> 4;
  const int split = blockIdx.x;       // 0..7
  const int qbase = blockIdx.y * 64;
  const int sbase = split * 2048 + w * 512;

  // Query (B) fragments: 4 tiles x 2 k-chunks, pinned (resident).
  short8 qh[4][2];
#pragma unroll
  for (int t = 0; t < 4; ++t) {
    const size_t pb = (size_t)((qbase >> 4) + t) * 1024 + (size_t)l * 8;
    qh[t][0] = *(const short8*)&Qh[pb];
    qh[t][1] = *(const short8*)&Qh[pb + 512];
  }
#pragma unroll
  for (int t = 0; t < 4; ++t) {
    pin8(qh[t][0]);
    pin8(qh[t][1]);
  }

  const ushort* pSh = Sh + (size_t)(sbase >> 4) * 1024 + (size_t)l * 8;
  const float* psq = sqS + sbase + lq * 4;

  // Copy-free double buffer: even steps use (a), odd steps use (b).
  short8 h0a = *(const short8*)(pSh);
  short8 h1a = *(const short8*)(pSh + 512);
  float4 sqa = *(const float4*)(psq);
  short8 h0b = *(const short8*)(pSh + 1024);
  short8 h1b = *(const short8*)(pSh + 1024 + 512);
  float4 sqb = *(const float4*)(psq + 16);

  float bmr[4] = {-FLT_BIG, -FLT_BIG, -FLT_BIG, -FLT_BIG};

  for (int st = 0; st < 32; st += 2) {
    STEP_COMPUTE(h0a, h1a, sqa);
    if (st + 2 < 32) {
      const int off = (st + 2) * 1024;
      h0a = *(const short8*)(pSh + off);
      h1a = *(const short8*)(pSh + off + 512);
      sqa = *(const float4*)(psq + (st + 2) * 16);
    }
    STEP_COMPUTE(h0b, h1b, sqb);
    if (st + 3 < 32) {
      const int off = (st + 3) * 1024;
      h0b = *(const short8*)(pSh + off);
      h1b = *(const short8*)(pSh + off + 512);
      sqb = *(const float4*)(psq + (st + 3) * 16);
    }
    if (((st + 1) & (BST - 1)) == (BST - 1)) {  // finished a bmin block
      const int gb = split * (128 / BST) + w * (32 / BST) + ((st + 1) / BST);
#pragma unroll
      for (int t = 0; t < 4; ++t) {
        float v = bmr[t];
        v = fmaxf(v, __shfl_xor(v, 16, 64));
        v = fmaxf(v, __shfl_xor(v, 32, 64));
        if (lq == 0) bmin[(size_t)(qbase + t * 16 + lm) * NSB + gb] = -2.0f * v;
        bmr[t] = -FLT_BIG;
      }
    }
  }
}

// ---------------------------------------------------------------------------
// Phase B: one BLOCK per query, 4 waves split the 64 dims (16 each).
// Per candidate 128-block: wave w loads 16 float2 columns (named scalars in
// an unrolled loop — NO register arrays), partial-dots into LDS
// (parity-double-buffered, 1 barrier per candidate), wave 0 combines,
// updates (key, idx), and finishes (lex reduce, label, out).
template <int SBLK>
__global__ __launch_bounds__(256) void k_phaseB(
    const float* __restrict__ S_T,   // [64][NTOT]
    const float* __restrict__ Q,     // [NTOT][64]
    const float* __restrict__ sqS, const float* __restrict__ sqQ,
    const int* __restrict__ maxS2, const float* __restrict__ bmin,
    const float* __restrict__ onehot, float* __restrict__ out) {
  constexpr int NSB = NTOT / SBLK;    // 128
  constexpr int NB64 = NSB / 64;      // 2
  static_assert(SBLK == 128, "dim-split phaseB assumes SBLK=128");

  __shared__ float sQ[64];
  __shared__ float2 part[2][4][64];   // [parity][wave][lane]
  const int lane = threadIdx.x & 63;
  const int w = threadIdx.x >> 6;
  const int q = blockIdx.x;

  if (threadIdx.x < 16)
    *(float4*)&sQ[threadIdx.x * 4] = *(const float4*)&Q[(size_t)q * DIM + threadIdx.x * 4];
  __syncthreads();

  // Per-query certified filter width (computed redundantly by all waves —
  // identical inputs => identical masks => aligned barriers below).
  const float ms2 = __int_as_float(*maxS2);
  const float eps = EPS_COEF * sqrtf(ms2 * sqQ[q]) + EPS_ABS;

  float bv0 = bmin[(size_t)q * NSB + lane];
  float bv1 = bmin[(size_t)q * NSB + 64 + lane];
  float m = fminf(bv0, bv1);
#pragma unroll
  for (int d = 1; d < 64; d <<= 1) m = fminf(m, __shfl_xor(m, d, 64));
  const float thr = m + eps;

  const int dbase = w * 16;           // this wave's dim slice
  float bk = FLT_BIG;
  int bi = 0;
  int par = 0;

#pragma unroll
  for (int j = 0; j < NB64; ++j) {
    unsigned long long msk = __ballot((j == 0 ? bv0 : bv1) <= thr);
    while (msk) {  // ascending block order; wave-uniform (identical masks)
      const int b = j * 64 + (__ffsll((long long)msk) - 1);
      msk &= msk - 1;
      const int s0 = b * SBLK + lane * 2;  // 2 consecutive supports per lane
      float a0 = 0.f, a1 = 0.f;
#pragma unroll
      for (int c = 0; c < 4; ++c) {   // 16 named-float2 loads, no arrays
        const float4 qv = *(const float4*)&sQ[dbase + c * 4];
        const float2 x0 = *(const float2*)&S_T[(size_t)(dbase + c * 4 + 0) * NTOT + s0];
        const float2 x1 = *(const float2*)&S_T[(size_t)(dbase + c * 4 + 1) * NTOT + s0];
        const float2 x2 = *(const float2*)&S_T[(size_t)(dbase + c * 4 + 2) * NTOT + s0];
        const float2 x3 = *(const float2*)&S_T[(size_t)(dbase + c * 4 + 3) * NTOT + s0];
        a0 = fmaf(qv.x, x0.x, a0); a1 = fmaf(qv.x, x0.y, a1);
        a0 = fmaf(qv.y, x1.x, a0); a1 = fmaf(qv.y, x1.y, a1);
        a0 = fmaf(qv.z, x2.x, a0); a1 = fmaf(qv.z, x2.y, a1);
        a0 = fmaf(qv.w, x3.x, a0); a1 = fmaf(qv.w, x3.y, a1);
      }
      part[par][w][lane] = make_float2(a0, a1);
      __syncthreads();  // aligned across waves (identical trip counts)
      if (w == 0) {
        const float2 p0 = part[par][0][lane];
        const float2 p1 = part[par][1][lane];
        const float2 p2 = part[par][2][lane];
        const float2 p3 = part[par][3][lane];
        const float s0d = (p0.x + p1.x) + (p2.x + p3.x);  // deterministic tree
        const float s1d = (p0.y + p1.y) + (p2.y + p3.y);
        const float2 sq2 = *(const float2*)&sqS[s0];
        const float k0 = fmaf(-2.f, s0d, sq2.x);
        const float k1 = fmaf(-2.f, s1d, sq2.y);
        bool u;  // ascending index, strict < => first minimum per lane
        u = k0 < bk; bk = u ? k0 : bk; bi = u ? s0 : bi;
        u = k1 < bk; bk = u ? k1 : bk; bi = u ? (s0 + 1) : bi;
      }
      par ^= 1;  // double buffer: next write targets the other half
    }
  }

  if (w == 0) {
    // Cross-lane lexicographic argmin on exact keys => first-index.
#pragma unroll
    for (int d = 1; d < 64; d <<= 1) {
      const float ok = __shfl_xor(bk, d, 64);
      const int oi = __shfl_xor(bi, d, 64);
      const bool u = (ok < bk) || (ok == bk && oi < bi);
      bk = u ? ok : bk;
      bi = u ? oi : bi;
    }
    // Label: one-hot rows exact {0,1}; first 1 == np.argmax.
    const float ov = onehot[(size_t)bi * 64 + lane];
    const unsigned long long lmask = __ballot(ov > 0.5f);
    const int label = __ffsll((long long)lmask) - 1;
    out[(size_t)q * 64 + lane] = (lane == label) ? 1.0f : 0.0f;
  }
}

// ---------------------------------------------------------------------------
// Fallback phaseB (small ws): R16's serial version, SBLK=256.
__global__ __launch_bounds__(256) void k_phaseB_serial(
    const float* __restrict__ S_T, const float* __restrict__ Q,
    const float* __restrict__ sqS, const float* __restrict__ sqQ,
    const int* __restrict__ maxS2, const float* __restrict__ bmin,
    const float* __restrict__ onehot, float* __restrict__ out) {
  constexpr int SBLK = 256;
  constexpr int NSB = NTOT / SBLK;
  __shared__ float sQrow[4][64];
  const int lane = threadIdx.x & 63;
  const int w = threadIdx.x >> 6;
  const int q = blockIdx.x * 4 + w;

  if (lane < 16)
    *(float4*)&sQrow[w][lane * 4] = *(const float4*)&Q[(size_t)q * DIM + lane * 4];
  __syncthreads();

  const float ms2 = __int_as_float(*maxS2);
  const float eps = EPS_COEF * sqrtf(ms2 * sqQ[q]) + EPS_ABS;

  const float bv = bmin[(size_t)q * NSB + lane];
  float m = bv;
#pragma unroll
  for (int d = 1; d < 64; d <<= 1) m = fminf(m, __shfl_xor(m, d, 64));
  unsigned long long msk = __ballot(bv <= m + eps);

  float bk = FLT_BIG;
  int bi = 0;
  while (msk) {
    const int b = __ffsll((long long)msk) - 1;
    msk &= msk - 1;
    const int s0 = b * SBLK + lane * 4;
    float a0 = 0.f, a1 = 0.f, a2 = 0.f, a3 = 0.f;
#pragma unroll
    for (int c = 0; c < 16; ++c) {
      const float4 qv = *(const float4*)&sQrow[w][c * 4];
      const float4 s0v = *(const float4*)&S_T[(size_t)(c * 4 + 0) * NTOT + s0];
      const float4 s1v = *(const float4*)&S_T[(size_t)(c * 4 + 1) * NTOT + s0];
      const float4 s2v = *(const float4*)&S_T[(size_t)(c * 4 + 2) * NTOT + s0];
      const float4 s3v = *(const float4*)&S_T[(size_t)(c * 4 + 3) * NTOT + s0];
      a0 = fmaf(qv.x, s0v.x, a0); a1 = fmaf(qv.x, s0v.y, a1);
      a2 = fmaf(qv.x, s0v.z, a2); a3 = fmaf(qv.x, s0v.w, a3);
      a0 = fmaf(qv.y, s1v.x, a0); a1 = fmaf(qv.y, s1v.y, a1);
      a2 = fmaf(qv.y, s1v.z, a2); a3 = fmaf(qv.y, s1v.w, a3);
      a0 = fmaf(qv.z, s2v.x, a0); a1 = fmaf(qv.z, s2v.y, a1);
      a2 = fmaf(qv.z, s2v.z, a2); a3 = fmaf(qv.z, s2v.w, a3);
      a0 = fmaf(qv.w, s3v.x, a0); a1 = fmaf(qv.w, s3v.y, a1);
      a2 = fmaf(qv.w, s3v.z, a2); a3 = fmaf(qv.w, s3v.w, a3);
    }
    const float4 sq4 = *(const float4*)&sqS[s0];
    const float k0 = fmaf(-2.f, a0, sq4.x);
    const float k1 = fmaf(-2.f, a1, sq4.y);
    const float k2 = fmaf(-2.f, a2, sq4.z);
    const float k3 = fmaf(-2.f, a3, sq4.w);
    bool u;
    u = k0 < bk; bk = u ? k0 : bk; bi = u ? s0 : bi;
    u = k1 < bk; bk = u ? k1 : bk; bi = u ? (s0 + 1) : bi;
    u = k2 < bk; bk = u ? k2 : bk; bi = u ? (s0 + 2) : bi;
    u = k3 < bk; bk = u ? k3 : bk; bi = u ? (s0 + 3) : bi;
  }
#pragma unroll
  for (int d = 1; d < 64; d <<= 1) {
    const float ok = __shfl_xor(bk, d, 64);
    const int oi = __shfl_xor(bi, d, 64);
    const bool u = (ok < bk) || (ok == bk && oi < bi);
    bk = u ? ok : bk;
    bi = u ? oi : bi;
  }
  const float ov = onehot[(size_t)bi * 64 + lane];
  const unsigned long long lmask = __ballot(ov > 0.5f);
  const int label = __ffsll((long long)lmask) - 1;
  out[(size_t)q * 64 + lane] = (lane == label) ? 1.0f : 0.0f;
}

// ---------------------------------------------------------------------------
extern "C" void kernel_launch(void* const* d_in, const int* in_sizes, int n_in,
                              void* d_out, int out_size, void* d_ws, size_t ws_size,
                              hipStream_t stream) {
  const float* S = (const float*)d_in[0];   // [16384][64]
  const float* Q = (const float*)d_in[1];   // [16384][64]
  const float* OH = (const float*)d_in[2];  // [16384][64]
  float* out = (float*)d_out;

  char* ws = (char*)d_ws;
  ushort* Sh = (ushort*)ws;                                  // [0, 2MB)
  ushort* Qh = (ushort*)(ws + (2u << 20));                   // [2, 4MB)
  float* S_T = (float*)(ws + (4u << 20));                    // [4, 8MB)
  float* sqS = (float*)(ws + (8u << 20));                    // 64 KB
  float* sqQ = (float*)(ws + (8u << 20) + (64u << 10));      // 64 KB
  int* mS2 = (int*)(ws + (8u << 20) + (128u << 10));         // 64 KB slot
  float* bmin = (float*)(ws + (8u << 20) + (192u << 10));    // up to 8 MB

  hipMemsetAsync(mS2, 0, 4, stream);  // maxS2 accumulator (stream op: ok)
  k_prep<<<dim3(512), 256, 0, stream>>>(S, Q, Sh, Qh, sqS, sqQ, S_T, mS2);

  if (ws_size >= (17u << 20)) {
    k_phaseA<8><<<dim3(8, NTOT / 64), 256, 0, stream>>>(Sh, Qh, sqS, bmin);
    k_phaseB<128><<<dim3(NTOT), 256, 0, stream>>>(S_T, Q, sqS, sqQ, mS2,
                                                  bmin, OH, out);
  } else {
    k_phaseA<16><<<dim3(8, NTOT / 64), 256, 0, stream>>>(Sh, Qh, sqS, bmin);
    k_phaseB_serial<<<dim3(NTOT / 4), 256, 0, stream>>>(S_T, Q, sqS, sqQ, mS2,
                                                        bmin, OH, out);
  }
  (void)in_sizes; (void)n_in; (void)out_size; (void)ws_size;
}

// Round 19
// 153.322 us; speedup vs baseline: 1.2618x; 1.0856x over previous
//
#include <hip/hip_runtime.h>

// KNN argmin over L2, round 19: R16 config (best, 161.7us) minus the
// memset dispatch and maxS2 atomic.
//
// Certified filter, self-contained: with c = 2^-9*1.01 <= 0.002 the f16
// cross error obeys c|s||q| <= 0.001(|s|^2+|q|^2) (AM-GM). phaseA folds
// the |s|^2 part into its C-init (cinit = -0.499*|s|^2, coefficient
// (1-c)/2 — free), so bmin encodes key_L(s) = 0.998|s|^2 - 2*cross_a with
//   bmin_truthblock <= key(s*) + 0.002|q|^2 <= any bmin + 0.004|q|^2.
// => rescoring all blocks with bmin <= min + 0.004*|q|^2 + 0.05 provably
// contains the true first argmin (slack covers f16 subnormal flush and
// fp32 accumulation rounding). The |q|^2 term is per-query and cancels in
// the relative comparison, so NO global maxS2 / atomic / memset needed.
//
// Everything else identical to R16: fused prep (f16 panels + S_T + norms),
// fp16 single-term phaseA (8 MFMA/step, pinned Q-frags, a/b prefetch,
// 128-granular bmin), serial S_T-based phaseB. Phase B exact fp32 keys,
// strict-< ascending + lexicographic cross-lane => np.argmin first-index.
//
// Round ledger (R15-R18): phaseB ~56-62us invariant under traffic halving,
// 4x shorter chains, 4x wave parallelism -> don't restructure phaseB;
// reduce dispatch count + filter width instead.

#define NTOT   16384
#define DIM    64
#define EPS_COEF 0.004f   // 2c with c=0.002 (>= 2^-9*1.01)
#define EPS_ABS  0.05f
#define CINIT_COEF (-0.499f)  // -(1-c)/2
#define FLT_BIG 3.4e38f

typedef __attribute__((ext_vector_type(8))) short short8;
typedef __attribute__((ext_vector_type(4))) float float4v;

__device__ __forceinline__ ushort f16_bits(float x) {
  union { _Float16 f; ushort u; } c;
  c.f = (_Float16)x;  // v_cvt_f16_f32, RNE
  return c.u;
}

// Opaque def: forbids rematerialization (forces register residency).
__device__ __forceinline__ void pin8(short8& v) {
  asm volatile("" : "+v"(v));
}

// ---------------------------------------------------------------------------
// Fused prep: blocks 0..255 -> S (f16 panels + sqS + S_T);
// blocks 256..511 -> Q (f16 panels + sqQ). Panel layout (R8-proven):
//   off(r,k) = (r>>4)*1024 + (k>>5)*512 + (((k&31)>>3)*16 + (r&15))*8 + (k&7)
__global__ __launch_bounds__(256) void k_prep(
    const float* __restrict__ S, const float* __restrict__ Q,
    ushort* __restrict__ Sh, ushort* __restrict__ Qh,
    float* __restrict__ sqS, float* __restrict__ sqQ,
    float* __restrict__ S_T) {
  __shared__ float tile[64][65];
  const int tid = threadIdx.x;
  const bool isS = blockIdx.x < 256;
  const int rbase = (blockIdx.x & 255) * 64;
  const float* __restrict__ src = isS ? S : Q;
  ushort* __restrict__ dh = isS ? Sh : Qh;

  const int tx = tid & 63;
  const int ty = tid >> 6;
#pragma unroll
  for (int i = 0; i < 16; ++i) {
    const int r = i * 4 + ty;
    tile[r][tx] = src[(size_t)(rbase + r) * DIM + tx];  // coalesced
  }
  __syncthreads();

  if (isS) {  // transposed copy (coalesced, pad-safe)
#pragma unroll
    for (int i = 0; i < 16; ++i) {
      const int d = i * 4 + ty;
      S_T[(size_t)d * NTOT + rbase + tx] = tile[tx][d];
    }
  }

  // Panel-swizzled f16; stores are lane-contiguous 16B.
  const int panel = tid >> 6;           // 0..3
  const int half = (tid >> 5) & 1;      // k-half
  const int slot0 = (tid & 31) * 2;     // slot = q8*16 + m
#pragma unroll
  for (int ss = 0; ss < 2; ++ss) {
    const int s = slot0 + ss;
    const int m = s & 15;
    const int q8 = s >> 4;
    const int row = panel * 16 + m;
    const int kb = half * 32 + q8 * 8;
    short8 hv;
#pragma unroll
    for (int j = 0; j < 8; ++j) hv[j] = (short)f16_bits(tile[row][kb + j]);
    const size_t goff =
        (size_t)((rbase >> 4) + panel) * 1024 + (size_t)half * 512 + (size_t)s * 8;
    *(short8*)&dh[goff] = hv;
  }

  // Row sum of squares.
  if (tid < 64) {
    float acc = 0.0f;
#pragma unroll
    for (int d = 0; d < DIM; ++d) {
      const float v = tile[tid][d];
      acc = fmaf(v, v, acc);
    }
    (isS ? sqS : sqQ)[rbase + tid] = acc;
  }
}

// ---------------------------------------------------------------------------
// Phase A: block = 4 waves; wave w: 64 queries x 512 supports.
// grid = (8 splits, 256 q-tiles). 16x16x32 f16 MFMA (fragment layout as the
// R4-R18 HW-verified family). C init -0.499*sq (error-absorbing); 2-MFMA
// chain per tile; fold block-max of a => bmin = -2*max = blockmin key_L.

#define MFMA16F(A, B, C) __builtin_amdgcn_mfma_f32_16x16x32_f16(A, B, C, 0, 0, 0)

#define STEP_COMPUTE(H0, H1, SQ)                                           \
  do {                                                                     \
    float4v cinit;                                                         \
    cinit[0] = CINIT_COEF * SQ.x;                                          \
    cinit[1] = CINIT_COEF * SQ.y;                                          \
    cinit[2] = CINIT_COEF * SQ.z;                                          \
    cinit[3] = CINIT_COEF * SQ.w;                                          \
    _Pragma("unroll")                                                      \
    for (int t = 0; t < 4; ++t) {                                          \
      float4v a = MFMA16F(H0, qh[t][0], cinit);                            \
      a = MFMA16F(H1, qh[t][1], a);                                        \
      bmr[t] = fmaxf(bmr[t], fmaxf(fmaxf(a[0], a[1]), fmaxf(a[2], a[3]))); \
    }                                                                      \
  } while (0)

template <int BST>  // steps per bmin block (8 -> 128-support granularity)
__global__ __launch_bounds__(256, 3) void k_phaseA(
    const ushort* __restrict__ Sh, const ushort* __restrict__ Qh,
    const float* __restrict__ sqS, float* __restrict__ bmin) {
  constexpr int NSB = NTOT / (16 * BST);
  const int tid = threadIdx.x;
  const int l = tid & 63;
  const int w = tid >> 6;
  const int lm = l & 15;
  const int lq = l >> 4;
  const int split = blockIdx.x;       // 0..7
  const int qbase = blockIdx.y * 64;
  const int sbase = split * 2048 + w * 512;

  // Query (B) fragments: 4 tiles x 2 k-chunks, pinned (resident).
  short8 qh[4][2];
#pragma unroll
  for (int t = 0; t < 4; ++t) {
    const size_t pb = (size_t)((qbase >> 4) + t) * 1024 + (size_t)l * 8;
    qh[t][0] = *(const short8*)&Qh[pb];
    qh[t][1] = *(const short8*)&Qh[pb + 512];
  }
#pragma unroll
  for (int t = 0; t < 4; ++t) {
    pin8(qh[t][0]);
    pin8(qh[t][1]);
  }

  const ushort* pSh = Sh + (size_t)(sbase >> 4) * 1024 + (size_t)l * 8;
  const float* psq = sqS + sbase + lq * 4;

  // Copy-free double buffer: even steps use (a), odd steps use (b).
  short8 h0a = *(const short8*)(pSh);
  short8 h1a = *(const short8*)(pSh + 512);
  float4 sqa = *(const float4*)(psq);
  short8 h0b = *(const short8*)(pSh + 1024);
  short8 h1b = *(const short8*)(pSh + 1024 + 512);
  float4 sqb = *(const float4*)(psq + 16);

  float bmr[4] = {-FLT_BIG, -FLT_BIG, -FLT_BIG, -FLT_BIG};

  for (int st = 0; st < 32; st += 2) {
    STEP_COMPUTE(h0a, h1a, sqa);
    if (st + 2 < 32) {
      const int off = (st + 2) * 1024;
      h0a = *(const short8*)(pSh + off);
      h1a = *(const short8*)(pSh + off + 512);
      sqa = *(const float4*)(psq + (st + 2) * 16);
    }
    STEP_COMPUTE(h0b, h1b, sqb);
    if (st + 3 < 32) {
      const int off = (st + 3) * 1024;
      h0b = *(const short8*)(pSh + off);
      h1b = *(const short8*)(pSh + off + 512);
      sqb = *(const float4*)(psq + (st + 3) * 16);
    }
    if (((st + 1) & (BST - 1)) == (BST - 1)) {  // finished a bmin block
      const int gb = split * (128 / BST) + w * (32 / BST) + ((st + 1) / BST);
#pragma unroll
      for (int t = 0; t < 4; ++t) {
        float v = bmr[t];
        v = fmaxf(v, __shfl_xor(v, 16, 64));
        v = fmaxf(v, __shfl_xor(v, 32, 64));
        if (lq == 0) bmin[(size_t)(qbase + t * 16 + lm) * NSB + gb] = -2.0f * v;
        bmr[t] = -FLT_BIG;
      }
    }
  }
}

// ---------------------------------------------------------------------------
// Phase B: one wave per query; serial coalesced rescore from S_T
// (R16-proven structure). eps = 0.004*|q|^2 + 0.05 (self-contained bound).
template <int SBLK>
__global__ __launch_bounds__(256) void k_phaseB(
    const float* __restrict__ S_T,   // [64][NTOT]
    const float* __restrict__ Q,     // [NTOT][64]
    const float* __restrict__ sqS, const float* __restrict__ sqQ,
    const float* __restrict__ bmin,
    const float* __restrict__ onehot, float* __restrict__ out) {
  constexpr int NSB = NTOT / SBLK;    // 128 or 64
  constexpr int NB64 = NSB / 64;
  constexpr int SPL = SBLK / 64;      // supports per lane: 2 or 4

  __shared__ float sQrow[4][64];
  const int lane = threadIdx.x & 63;
  const int w = threadIdx.x >> 6;
  const int q = blockIdx.x * 4 + w;

  if (lane < 16)
    *(float4*)&sQrow[w][lane * 4] = *(const float4*)&Q[(size_t)q * DIM + lane * 4];
  __syncthreads();

  // Per-query certified filter width (no global data needed).
  const float eps = EPS_COEF * sqQ[q] + EPS_ABS;

  float bv[NB64];
#pragma unroll
  for (int j = 0; j < NB64; ++j) bv[j] = bmin[(size_t)q * NSB + j * 64 + lane];
  float m = bv[0];
#pragma unroll
  for (int j = 1; j < NB64; ++j) m = fminf(m, bv[j]);
#pragma unroll
  for (int d = 1; d < 64; d <<= 1) m = fminf(m, __shfl_xor(m, d, 64));
  const float thr = m + eps;

  float bk = FLT_BIG;
  int bi = 0;
#pragma unroll
  for (int j = 0; j < NB64; ++j) {
    unsigned long long msk = __ballot(bv[j] <= thr);
    while (msk) {  // ascending block order; wave-uniform control
      const int b = j * 64 + (__ffsll((long long)msk) - 1);
      msk &= msk - 1;
      const int s0 = b * SBLK + lane * SPL;
      if (SPL == 2) {
        float a0 = 0.f, a1 = 0.f;
#pragma unroll
        for (int c = 0; c < 16; ++c) {
          const float4 qv = *(const float4*)&sQrow[w][c * 4];
          const float2 x0 = *(const float2*)&S_T[(size_t)(c * 4 + 0) * NTOT + s0];
          const float2 x1 = *(const float2*)&S_T[(size_t)(c * 4 + 1) * NTOT + s0];
          const float2 x2 = *(const float2*)&S_T[(size_t)(c * 4 + 2) * NTOT + s0];
          const float2 x3 = *(const float2*)&S_T[(size_t)(c * 4 + 3) * NTOT + s0];
          a0 = fmaf(qv.x, x0.x, a0); a1 = fmaf(qv.x, x0.y, a1);
          a0 = fmaf(qv.y, x1.x, a0); a1 = fmaf(qv.y, x1.y, a1);
          a0 = fmaf(qv.z, x2.x, a0); a1 = fmaf(qv.z, x2.y, a1);
          a0 = fmaf(qv.w, x3.x, a0); a1 = fmaf(qv.w, x3.y, a1);
        }
        const float2 sq2 = *(const float2*)&sqS[s0];
        const float k0 = fmaf(-2.f, a0, sq2.x);
        const float k1 = fmaf(-2.f, a1, sq2.y);
        bool u;  // ascending index, strict < => first minimum per lane
        u = k0 < bk; bk = u ? k0 : bk; bi = u ? s0 : bi;
        u = k1 < bk; bk = u ? k1 : bk; bi = u ? (s0 + 1) : bi;
      } else {
        float a0 = 0.f, a1 = 0.f, a2 = 0.f, a3 = 0.f;
#pragma unroll
        for (int c = 0; c < 16; ++c) {
          const float4 qv = *(const float4*)&sQrow[w][c * 4];
          const float4 s0v = *(const float4*)&S_T[(size_t)(c * 4 + 0) * NTOT + s0];
          const float4 s1v = *(const float4*)&S_T[(size_t)(c * 4 + 1) * NTOT + s0];
          const float4 s2v = *(const float4*)&S_T[(size_t)(c * 4 + 2) * NTOT + s0];
          const float4 s3v = *(const float4*)&S_T[(size_t)(c * 4 + 3) * NTOT + s0];
          a0 = fmaf(qv.x, s0v.x, a0); a1 = fmaf(qv.x, s0v.y, a1);
          a2 = fmaf(qv.x, s0v.z, a2); a3 = fmaf(qv.x, s0v.w, a3);
          a0 = fmaf(qv.y, s1v.x, a0); a1 = fmaf(qv.y, s1v.y, a1);
          a2 = fmaf(qv.y, s1v.z, a2); a3 = fmaf(qv.y, s1v.w, a3);
          a0 = fmaf(qv.z, s2v.x, a0); a1 = fmaf(qv.z, s2v.y, a1);
          a2 = fmaf(qv.z, s2v.z, a2); a3 = fmaf(qv.z, s2v.w, a3);
          a0 = fmaf(qv.w, s3v.x, a0); a1 = fmaf(qv.w, s3v.y, a1);
          a2 = fmaf(qv.w, s3v.z, a2); a3 = fmaf(qv.w, s3v.w, a3);
        }
        const float4 sq4 = *(const float4*)&sqS[s0];
        const float k0 = fmaf(-2.f, a0, sq4.x);
        const float k1 = fmaf(-2.f, a1, sq4.y);
        const float k2 = fmaf(-2.f, a2, sq4.z);
        const float k3 = fmaf(-2.f, a3, sq4.w);
        bool u;
        u = k0 < bk; bk = u ? k0 : bk; bi = u ? s0 : bi;
        u = k1 < bk; bk = u ? k1 : bk; bi = u ? (s0 + 1) : bi;
        u = k2 < bk; bk = u ? k2 : bk; bi = u ? (s0 + 2) : bi;
        u = k3 < bk; bk = u ? k3 : bk; bi = u ? (s0 + 3) : bi;
      }
    }
  }
  // Cross-lane lexicographic argmin on exact keys => first-index semantics.
#pragma unroll
  for (int d = 1; d < 64; d <<= 1) {
    const float ok = __shfl_xor(bk, d, 64);
    const int oi = __shfl_xor(bi, d, 64);
    const bool u = (ok < bk) || (ok == bk && oi < bi);
    bk = u ? ok : bk;
    bi = u ? oi : bi;
  }
  // Label: one-hot rows exact {0,1}; first 1 == np.argmax.
  const float ov = onehot[(size_t)bi * 64 + lane];
  const unsigned long long lmask = __ballot(ov > 0.5f);
  const int label = __ffsll((long long)lmask) - 1;
  out[(size_t)q * 64 + lane] = (lane == label) ? 1.0f : 0.0f;
}

// ---------------------------------------------------------------------------
extern "C" void kernel_launch(void* const* d_in, const int* in_sizes, int n_in,
                              void* d_out, int out_size, void* d_ws, size_t ws_size,
                              hipStream_t stream) {
  const float* S = (const float*)d_in[0];   // [16384][64]
  const float* Q = (const float*)d_in[1];   // [16384][64]
  const float* OH = (const float*)d_in[2];  // [16384][64]
  float* out = (float*)d_out;

  char* ws = (char*)d_ws;
  ushort* Sh = (ushort*)ws;                                  // [0, 2MB)
  ushort* Qh = (ushort*)(ws + (2u << 20));                   // [2, 4MB)
  float* S_T = (float*)(ws + (4u << 20));                    // [4, 8MB)
  float* sqS = (float*)(ws + (8u << 20));                    // 64 KB
  float* sqQ = (float*)(ws + (8u << 20) + (64u << 10));      // 64 KB
  float* bmin = (float*)(ws + (8u << 20) + (128u << 10));    // up to 8 MB

  k_prep<<<dim3(512), 256, 0, stream>>>(S, Q, Sh, Qh, sqS, sqQ, S_T);

  // 128-granular bmin (8 MB) if workspace allows (proven >=20 MB in R14);
  // else 256-granular (4 MB). Need: 8.13 + 8 = 16.13 MB / 12.13 MB.
  if (ws_size >= (17u << 20)) {
    k_phaseA<8><<<dim3(8, NTOT / 64), 256, 0, stream>>>(Sh, Qh, sqS, bmin);
    k_phaseB<128><<<dim3(NTOT / 4), 256, 0, stream>>>(S_T, Q, sqS, sqQ,
                                                      bmin, OH, out);
  } else {
    k_phaseA<16><<<dim3(8, NTOT / 64), 256, 0, stream>>>(Sh, Qh, sqS, bmin);
    k_phaseB<256><<<dim3(NTOT / 4), 256, 0, stream>>>(S_T, Q, sqS, sqQ,
                                                      bmin, OH, out);
  }
  (void)in_sizes; (void)n_in; (void)out_size; (void)ws_size;
}